// Round 1
// baseline (812.291 us; speedup 1.0000x reference)
//
#include <hip/hip_runtime.h>

// WindowAttention fused kernel for MI355X (gfx950).
// One block = one window (N=49 tokens padded to 64, C=128, H=4 heads, hd=32).
// 4 waves/block. bf16 MFMA (16x16x32) for all GEMM-shaped work, fp32 softmax.

typedef short bf16x8 __attribute__((ext_vector_type(8)));
typedef float f32x4 __attribute__((ext_vector_type(4)));

#define NTOK 49
#define CDIM 128
#define NHEAD 4
#define HD 32

__device__ __forceinline__ unsigned short f2bf(float f) {
    // round-to-nearest-even fp32 -> bf16
    unsigned int u = __float_as_uint(f);
    u += 0x7fffu + ((u >> 16) & 1u);
    return (unsigned short)(u >> 16);
}

__global__ void prep_kernel(const float* __restrict__ qkv_w,
                            const float* __restrict__ proj_w,
                            unsigned short* __restrict__ wq,
                            unsigned short* __restrict__ wp) {
    int i = blockIdx.x * 256 + threadIdx.x;
    if (i < 384 * 128) wq[i] = f2bf(qkv_w[i]);   // row-major [384][128] = B^T layout
    if (i < 128 * 128) wp[i] = f2bf(proj_w[i]);  // row-major [128][128]
}

// LDS map (64 KB total -> 2 blocks/CU):
//  region A [0,16384):     phase1: xb bf16[64][128] swz | phase2: mask f32[2401]@0,
//                          rel u8[2401]@9604, rpb f32[676]@12008 | phase2end/3: attnout bf16[64][128] swz
//  region B [16384,49152): phase1/2: qkvb bf16[64][256] swz (q cols 0-127, k cols 128-255)
//                          post-QK barrier: P bf16 per-wave [64][64] swz @ 16384+h*8192
//  region C [49152,65536): vt bf16[128][64] swz (v transposed: row = h*32+d, col = token)

__global__ void __launch_bounds__(256, 2)
win_attn_kernel(const float* __restrict__ x, const float* __restrict__ mask,
                const float* __restrict__ qkv_b, const float* __restrict__ proj_b,
                const float* __restrict__ rpb, const int* __restrict__ relidx,
                const unsigned short* __restrict__ wq, const unsigned short* __restrict__ wp,
                float* __restrict__ out, int nW) {
    __shared__ __align__(16) unsigned char smem[65536];

    const int tid  = threadIdx.x;
    const int wid  = tid >> 6;
    const int lane = tid & 63;
    const int l15  = lane & 15;
    const int lhi  = lane >> 4;
    const int win  = blockIdx.x;
    const int wm   = win % nW;

    // ---------- phase 0: stage x window -> LDS bf16 (swizzled), zero pad rows ----------
    const float* xw = x + (size_t)win * (NTOK * CDIM);
    for (int i = tid; i < NTOK * 32; i += 256) {          // 49 rows x 32 chunks of 4 floats
        float4 v = reinterpret_cast<const float4*>(xw)[i];
        int row  = i >> 5;
        int colB = (i & 31) * 8;
        uint2 u;
        u.x = (unsigned)f2bf(v.x) | ((unsigned)f2bf(v.y) << 16);
        u.y = (unsigned)f2bf(v.z) | ((unsigned)f2bf(v.w) << 16);
        *reinterpret_cast<uint2*>(&smem[row * 256 + (colB ^ ((row & 7) << 4))]) = u;
    }
    for (int i = tid; i < 15 * 32; i += 256) {            // rows 49..63 = 0
        int row = 49 + (i >> 5);
        int colB = (i & 31) * 8;
        uint2 z; z.x = 0u; z.y = 0u;
        *reinterpret_cast<uint2*>(&smem[row * 256 + colB]) = z;  // XOR is a bijection per row
    }
    __syncthreads();  // b0

    // ---------- phase 1: QKV GEMM  (M=64 pad, K=128, Ncols=384; wave w owns cols [96w,96w+96)) ----------
    bf16x8 af[4][4];
#pragma unroll
    for (int mt = 0; mt < 4; ++mt)
#pragma unroll
        for (int ks = 0; ks < 4; ++ks) {
            int row = l15 + 16 * mt;
            int colB = lhi * 16 + ks * 64;
            af[mt][ks] = *reinterpret_cast<const bf16x8*>(&smem[row * 256 + (colB ^ ((row & 7) << 4))]);
        }
#pragma unroll
    for (int nt = 0; nt < 6; ++nt) {
        const int colg = wid * 96 + nt * 16 + l15;   // global qkv output column for this lane
        f32x4 acc[4];
#pragma unroll
        for (int mt = 0; mt < 4; ++mt) { f32x4 z = {0.f, 0.f, 0.f, 0.f}; acc[mt] = z; }
        const unsigned short* wql = wq + colg * 128 + lhi * 8;
#pragma unroll
        for (int ks = 0; ks < 4; ++ks) {
            bf16x8 bfr = *reinterpret_cast<const bf16x8*>(wql + ks * 32);
#pragma unroll
            for (int mt = 0; mt < 4; ++mt)
                acc[mt] = __builtin_amdgcn_mfma_f32_16x16x32_bf16(af[mt][ks], bfr, acc[mt], 0, 0, 0);
        }
        const float bias = qkv_b[colg];
        if (colg < 256) {  // q,k -> qkvb (row = token, col = channel), wave-uniform branch
#pragma unroll
            for (int mt = 0; mt < 4; ++mt)
#pragma unroll
                for (int r = 0; r < 4; ++r) {
                    int row = 16 * mt + lhi * 4 + r;
                    *reinterpret_cast<unsigned short*>(
                        &smem[16384 + row * 512 + ((colg * 2) ^ ((row & 7) << 4))]) = f2bf(acc[mt][r] + bias);
                }
        } else {           // v -> vt transposed (row = channel, col = token), packed 8B writes
            const int vr = colg - 256;  // 0..127
#pragma unroll
            for (int mt = 0; mt < 4; ++mt) {
                int kb = 16 * mt + lhi * 4;   // 4 consecutive tokens
                uint2 u;
                u.x = (unsigned)f2bf(acc[mt][0] + bias) | ((unsigned)f2bf(acc[mt][1] + bias) << 16);
                u.y = (unsigned)f2bf(acc[mt][2] + bias) | ((unsigned)f2bf(acc[mt][3] + bias) << 16);
                *reinterpret_cast<uint2*>(&smem[49152 + vr * 128 + ((kb * 2) ^ ((vr & 7) << 4))]) = u;
            }
        }
    }
    __syncthreads();  // b1: qkvb/vt ready; xb dead

    // ---------- phase 2 staging: mask/rel/rpb -> region A (overlaps with QK^T below) ----------
    float* maskLds = reinterpret_cast<float*>(smem);
    unsigned char* relLds = smem + 9604;
    float* rpbLds = reinterpret_cast<float*>(smem + 12008);
    const float* mrow = mask + (size_t)wm * (NTOK * NTOK);
    for (int i = tid; i < NTOK * NTOK; i += 256) maskLds[i] = mrow[i];
    for (int i = tid; i < NTOK * NTOK; i += 256) relLds[i] = (unsigned char)relidx[i];
    for (int i = tid; i < 169 * NHEAD; i += 256) rpbLds[i] = rpb[i];

    // ---------- phase 2: per-head attention (wave h = head h) ----------
    const int h = wid;
    bf16x8 qf[4], kf[4];
#pragma unroll
    for (int t = 0; t < 4; ++t) {
        int row = l15 + 16 * t;
        int cq = h * 64 + lhi * 16;
        int ck = 256 + h * 64 + lhi * 16;
        qf[t] = *reinterpret_cast<const bf16x8*>(&smem[16384 + row * 512 + (cq ^ ((row & 7) << 4))]);
        kf[t] = *reinterpret_cast<const bf16x8*>(&smem[16384 + row * 512 + (ck ^ ((row & 7) << 4))]);
    }
    f32x4 s[4][4];
#pragma unroll
    for (int mt = 0; mt < 4; ++mt)
#pragma unroll
        for (int nt = 0; nt < 4; ++nt) {
            f32x4 z = {0.f, 0.f, 0.f, 0.f};
            s[mt][nt] = __builtin_amdgcn_mfma_f32_16x16x32_bf16(qf[mt], kf[nt], z, 0, 0, 0);
        }
    __syncthreads();  // b2: all q/k reads done (P may alias qkvb); mask/rel/rpb staged

    // logits = s*scale + bias[rel[q][k]][h] + mask[wm][q][k]; pad cols -> -inf
    const float scale = 0.17677669529663687f;  // 1/sqrt(32)
    float inv[4][4];
#pragma unroll
    for (int mt = 0; mt < 4; ++mt)
#pragma unroll
        for (int nt = 0; nt < 4; ++nt)
#pragma unroll
            for (int r = 0; r < 4; ++r) {
                int q = 16 * mt + lhi * 4 + r;
                int kk = 16 * nt + l15;
                float l = -1e30f;
                if (kk < NTOK) {
                    l = s[mt][nt][r] * scale;
                    if (q < NTOK) {
                        int idx = relLds[q * NTOK + kk];
                        l += rpbLds[idx * NHEAD + h] + maskLds[q * NTOK + kk];
                    }
                }
                s[mt][nt][r] = l;
            }
#pragma unroll
    for (int mt = 0; mt < 4; ++mt)
#pragma unroll
        for (int r = 0; r < 4; ++r) {
            float m = fmaxf(fmaxf(s[mt][0][r], s[mt][1][r]), fmaxf(s[mt][2][r], s[mt][3][r]));
            m = fmaxf(m, __shfl_xor(m, 1));
            m = fmaxf(m, __shfl_xor(m, 2));
            m = fmaxf(m, __shfl_xor(m, 4));
            m = fmaxf(m, __shfl_xor(m, 8));
            float sum = 0.f;
#pragma unroll
            for (int nt = 0; nt < 4; ++nt) {
                float p = __expf(s[mt][nt][r] - m);
                s[mt][nt][r] = p;
                sum += p;
            }
            sum += __shfl_xor(sum, 1);
            sum += __shfl_xor(sum, 2);
            sum += __shfl_xor(sum, 4);
            sum += __shfl_xor(sum, 8);
            inv[mt][r] = 1.0f / sum;
        }
    // write unnormalized P (bf16) into per-wave buffer aliasing qkvb
#pragma unroll
    for (int mt = 0; mt < 4; ++mt)
#pragma unroll
        for (int nt = 0; nt < 4; ++nt)
#pragma unroll
            for (int r = 0; r < 4; ++r) {
                int q = 16 * mt + lhi * 4 + r;
                int kk = 16 * nt + l15;
                *reinterpret_cast<unsigned short*>(
                    &smem[16384 + h * 8192 + q * 128 + ((kk * 2) ^ ((q & 7) << 4))]) = f2bf(s[mt][nt][r]);
            }
    __syncthreads();  // b3: last mask/rel reads done (attnout may alias region A); P visible

    // PV: out[64 q][32 d] = P[64x64] @ V[64x32]
    bf16x8 vf[2][2];
#pragma unroll
    for (int nt = 0; nt < 2; ++nt)
#pragma unroll
        for (int ks = 0; ks < 2; ++ks) {
            int vr = h * 32 + 16 * nt + l15;
            int colB = lhi * 16 + ks * 64;
            vf[nt][ks] = *reinterpret_cast<const bf16x8*>(&smem[49152 + vr * 128 + (colB ^ ((vr & 7) << 4))]);
        }
    f32x4 o[4][2];
#pragma unroll
    for (int mt = 0; mt < 4; ++mt)
#pragma unroll
        for (int nt = 0; nt < 2; ++nt) { f32x4 z = {0.f, 0.f, 0.f, 0.f}; o[mt][nt] = z; }
#pragma unroll
    for (int mt = 0; mt < 4; ++mt)
#pragma unroll
        for (int ks = 0; ks < 2; ++ks) {
            int row = l15 + 16 * mt;
            int colB = lhi * 16 + ks * 64;
            bf16x8 pf = *reinterpret_cast<const bf16x8*>(
                &smem[16384 + h * 8192 + row * 128 + (colB ^ ((row & 7) << 4))]);
#pragma unroll
            for (int nt = 0; nt < 2; ++nt)
                o[mt][nt] = __builtin_amdgcn_mfma_f32_16x16x32_bf16(pf, vf[nt][ks], o[mt][nt], 0, 0, 0);
        }
    // normalize + write attnout (region A, aliases dead xb/mask)
#pragma unroll
    for (int mt = 0; mt < 4; ++mt)
#pragma unroll
        for (int nt = 0; nt < 2; ++nt)
#pragma unroll
            for (int r = 0; r < 4; ++r) {
                int q = 16 * mt + lhi * 4 + r;
                int col = h * 32 + 16 * nt + l15;
                *reinterpret_cast<unsigned short*>(
                    &smem[q * 256 + ((col * 2) ^ ((q & 7) << 4))]) = f2bf(o[mt][nt][r] * inv[mt][r]);
            }
    __syncthreads();  // b4: attnout ready

    // ---------- phase 3: proj GEMM (M=64, K=128, N=128; wave w owns cols [32w,32w+32)) ----------
    bf16x8 aof[4][4];
#pragma unroll
    for (int mt = 0; mt < 4; ++mt)
#pragma unroll
        for (int ks = 0; ks < 4; ++ks) {
            int row = l15 + 16 * mt;
            int colB = lhi * 16 + ks * 64;
            aof[mt][ks] = *reinterpret_cast<const bf16x8*>(&smem[row * 256 + (colB ^ ((row & 7) << 4))]);
        }
#pragma unroll
    for (int nt = 0; nt < 2; ++nt) {
        const int colg = wid * 32 + nt * 16 + l15;
        f32x4 c[4];
#pragma unroll
        for (int mt = 0; mt < 4; ++mt) { f32x4 z = {0.f, 0.f, 0.f, 0.f}; c[mt] = z; }
        const unsigned short* wpl = wp + colg * 128 + lhi * 8;
#pragma unroll
        for (int ks = 0; ks < 4; ++ks) {
            bf16x8 bfr = *reinterpret_cast<const bf16x8*>(wpl + ks * 32);
#pragma unroll
            for (int mt = 0; mt < 4; ++mt)
                c[mt] = __builtin_amdgcn_mfma_f32_16x16x32_bf16(aof[mt][ks], bfr, c[mt], 0, 0, 0);
        }
        const float pb = proj_b[colg];
        float* orow = out + (size_t)win * (NTOK * CDIM) + colg;
#pragma unroll
        for (int mt = 0; mt < 4; ++mt)
#pragma unroll
            for (int r = 0; r < 4; ++r) {
                int q = 16 * mt + lhi * 4 + r;
                if (q < NTOK) orow[q * CDIM] = c[mt][r] + pb;
            }
    }
}

extern "C" void kernel_launch(void* const* d_in, const int* in_sizes, int n_in,
                              void* d_out, int out_size, void* d_ws, size_t ws_size,
                              hipStream_t stream) {
    const float* x      = (const float*)d_in[0];
    const float* mask   = (const float*)d_in[1];
    const float* qkv_w  = (const float*)d_in[2];
    const float* qkv_b  = (const float*)d_in[3];
    const float* proj_w = (const float*)d_in[4];
    const float* proj_b = (const float*)d_in[5];
    const float* rpb    = (const float*)d_in[6];
    const int*   relidx = (const int*)d_in[7];

    const int Bw = in_sizes[0] / (NTOK * CDIM);       // 16384
    const int nW = in_sizes[1] / (NTOK * NTOK);       // 1024

    unsigned short* wq = (unsigned short*)d_ws;       // 384*128 bf16
    unsigned short* wp = wq + 384 * 128;              // 128*128 bf16

    prep_kernel<<<dim3((384 * 128 + 255) / 256), dim3(256), 0, stream>>>(qkv_w, proj_w, wq, wp);
    win_attn_kernel<<<dim3(Bw), dim3(256), 0, stream>>>(x, mask, qkv_b, proj_b, rpb, relidx,
                                                        wq, wp, (float*)d_out, nW);
}

// Round 2
// 658.949 us; speedup vs baseline: 1.2327x; 1.2327x over previous
//
#include <hip/hip_runtime.h>

// WindowAttention fused kernel for MI355X (gfx950) — R1.
// One block = one window (N=49 pad 64, C=128, H=4, hd=32), 4 waves.
// All MFMAs "swapped" (mfma(W,x) etc.) so epilogue fragments hold 4 consecutive
// channels at fixed token -> packed 8B LDS writes / float4 global stores.
// QK^T adds (rpb+mask) via the MFMA C operand from a precomputed bf16 table.

typedef short bf16x8 __attribute__((ext_vector_type(8)));
typedef float f32x4 __attribute__((ext_vector_type(4)));
#define MFMA __builtin_amdgcn_mfma_f32_16x16x32_bf16

#define NTOK 49
#define CDIM 128
#define NHEAD 4

__device__ __forceinline__ unsigned short f2bf(float f) {
    unsigned int u = __float_as_uint(f);
    u += 0x7fffu + ((u >> 16) & 1u);
    return (unsigned short)(u >> 16);
}
__device__ __forceinline__ unsigned pack2bf(float a, float b) {
    return (unsigned)f2bf(a) | ((unsigned)f2bf(b) << 16);
}
__device__ __forceinline__ float bflo(unsigned u) { return __uint_as_float(u << 16); }
__device__ __forceinline__ float bfhi(unsigned u) { return __uint_as_float(u & 0xffff0000u); }

union BF8 { bf16x8 v; unsigned u[4]; };

__global__ void prep_w(const float* __restrict__ qkv_w, const float* __restrict__ proj_w,
                       unsigned short* __restrict__ wq, unsigned short* __restrict__ wp) {
    int i = blockIdx.x * 256 + threadIdx.x;
    if (i < 384 * 128) wq[i] = f2bf(qkv_w[i]);   // [out_ch][in_ch] row-major
    if (i < 128 * 128) wp[i] = f2bf(proj_w[i]);
}

// comb[wm][h][q64][key64] bf16 = rpb[rel[q][k]][h] + mask[wm][q][k]; pads: key>=49 -> -1e30, q>=49 -> 0
__global__ void prep_comb(const float* __restrict__ mask, const float* __restrict__ rpb,
                          const int* __restrict__ rel, unsigned short* __restrict__ comb, int nW) {
    int idx = blockIdx.x * 256 + threadIdx.x;
    int key = idx & 63;
    int q   = (idx >> 6) & 63;
    int h   = (idx >> 12) & 3;
    int wm  = idx >> 14;
    if (wm >= nW) return;
    float v;
    if (key >= NTOK)      v = -1e30f;
    else if (q >= NTOK)   v = 0.0f;
    else v = rpb[rel[q * NTOK + key] * NHEAD + h] + mask[(size_t)wm * (NTOK * NTOK) + q * NTOK + key];
    comb[idx] = f2bf(v);
}

// LDS (48 KB -> 3 blocks/CU):
//  [0,16384):     vt bf16[128 ch][64 tok] swz   -> after b3: attnout bf16[64 tok][128 ch] swz
//  [16384,49152): qk bf16[64 tok][256 ch] swz   -> after b2: P_h bf16[64 q][64 key] swz @ 16384+h*8192
template <bool USE_COMB>
__global__ void __launch_bounds__(256, 3)
win_attn_kernel(const float* __restrict__ x,
                const float* __restrict__ qkv_b, const float* __restrict__ proj_b,
                const unsigned short* __restrict__ wq, const unsigned short* __restrict__ wp,
                const unsigned short* __restrict__ comb,
                const float* __restrict__ mask, const float* __restrict__ rpb,
                const int* __restrict__ rel,
                float* __restrict__ out, int nW) {
    __shared__ __align__(16) unsigned char smem[49152];

    const int tid = threadIdx.x;
    const int wid = tid >> 6;
    const int lane = tid & 63;
    const int l15 = lane & 15;
    const int lhi = lane >> 4;
    const int win = blockIdx.x;
    const int wm  = win % nW;

    // ---------- phase 1: load x fragments from global (B operand: tok=l15, k=in_ch) ----------
    const float* xw = x + (size_t)win * (NTOK * CDIM);
    bf16x8 xf[4][4];
#pragma unroll
    for (int tt = 0; tt < 4; ++tt) {
        const int tok = tt * 16 + l15;
        const bool valid = tok < NTOK;
#pragma unroll
        for (int ks = 0; ks < 4; ++ks) {
            float4 a, b;
            a.x = a.y = a.z = a.w = 0.f;
            b.x = b.y = b.z = b.w = 0.f;
            if (valid) {
                const float* p = xw + tok * CDIM + ks * 32 + lhi * 8;
                a = reinterpret_cast<const float4*>(p)[0];
                b = reinterpret_cast<const float4*>(p)[1];
            }
            BF8 t;
            t.u[0] = pack2bf(a.x, a.y);
            t.u[1] = pack2bf(a.z, a.w);
            t.u[2] = pack2bf(b.x, b.y);
            t.u[3] = pack2bf(b.z, b.w);
            xf[tt][ks] = t.v;
        }
    }

    // ---------- QKV GEMM: wave w owns output channels [96w, 96w+96) ----------
    const float scale = 0.17677669529663687f;  // 1/sqrt(32)
#pragma unroll
    for (int ct = 0; ct < 6; ++ct) {
        const int cgb = wid * 96 + ct * 16;
        bf16x8 wf[4];
#pragma unroll
        for (int ks = 0; ks < 4; ++ks)
            wf[ks] = *reinterpret_cast<const bf16x8*>(wq + (cgb + l15) * CDIM + ks * 32 + lhi * 8);
        if (cgb < 256) {
            // q/k: swapped -> lane holds 4 consecutive channels at fixed token
            const float4 b4 = *reinterpret_cast<const float4*>(qkv_b + cgb + lhi * 4);
            const float sc = (cgb < 128) ? scale : 1.0f;
#pragma unroll
            for (int tt = 0; tt < 4; ++tt) {
                f32x4 acc = {0.f, 0.f, 0.f, 0.f};
#pragma unroll
                for (int ks = 0; ks < 4; ++ks) acc = MFMA(wf[ks], xf[tt][ks], acc, 0, 0, 0);
                const int tok = tt * 16 + l15;
                uint2 u;
                u.x = pack2bf((acc[0] + b4.x) * sc, (acc[1] + b4.y) * sc);
                u.y = pack2bf((acc[2] + b4.z) * sc, (acc[3] + b4.w) * sc);
                const int colB = (cgb + lhi * 4) * 2;
                *reinterpret_cast<uint2*>(&smem[16384 + tok * 512 + (colB ^ ((tok & 7) << 4))]) = u;
            }
        } else {
            // v: normal -> lane holds 4 consecutive tokens at fixed channel -> vt[ch][tok]
            const float bsc = qkv_b[cgb + l15];
            const int vr = cgb - 256 + l15;
#pragma unroll
            for (int tt = 0; tt < 4; ++tt) {
                f32x4 acc = {0.f, 0.f, 0.f, 0.f};
#pragma unroll
                for (int ks = 0; ks < 4; ++ks) acc = MFMA(xf[tt][ks], wf[ks], acc, 0, 0, 0);
                const int tokb = tt * 16 + lhi * 4;
                uint2 u;
                u.x = pack2bf(acc[0] + bsc, acc[1] + bsc);
                u.y = pack2bf(acc[2] + bsc, acc[3] + bsc);
                *reinterpret_cast<uint2*>(&smem[vr * 128 + ((tokb * 2) ^ ((vr & 7) << 4))]) = u;
            }
        }
    }
    __syncthreads();  // b1: qk + vt ready

    // ---------- phase 2: attention, wave = head ----------
    const int h = wid;

    // preload comb fragments early (L3 latency hides under QK)
    uint2 cb[4][4];
    if (USE_COMB) {
        const unsigned short* cwh = comb + ((size_t)(wm * NHEAD + h) << 12);
#pragma unroll
        for (int qt = 0; qt < 4; ++qt)
#pragma unroll
            for (int kt = 0; kt < 4; ++kt)
                cb[qt][kt] = *reinterpret_cast<const uint2*>(cwh + (qt * 16 + l15) * 64 + kt * 16 + lhi * 4);
    }

    bf16x8 qf[4], kf[4], vf[2][2];
#pragma unroll
    for (int t = 0; t < 4; ++t) {
        const int tok = t * 16 + l15;
        const int cq = (h * 32 + lhi * 8) * 2;
        const int ck = (128 + h * 32 + lhi * 8) * 2;
        qf[t] = *reinterpret_cast<const bf16x8*>(&smem[16384 + tok * 512 + (cq ^ ((tok & 7) << 4))]);
        kf[t] = *reinterpret_cast<const bf16x8*>(&smem[16384 + tok * 512 + (ck ^ ((tok & 7) << 4))]);
    }
#pragma unroll
    for (int dt = 0; dt < 2; ++dt)
#pragma unroll
        for (int ks = 0; ks < 2; ++ks) {
            const int vr = h * 32 + dt * 16 + l15;
            const int colB = (ks * 32 + lhi * 8) * 2;
            vf[dt][ks] = *reinterpret_cast<const bf16x8*>(&smem[vr * 128 + (colB ^ ((vr & 7) << 4))]);
        }

    // QK^T (swapped): sv[kt] lane holds S[key=16kt+lhi*4+r][q=16qt+l15], C = comb addend
    float inv[4];
    unsigned pw[4][4][2];
#pragma unroll
    for (int qt = 0; qt < 4; ++qt) {
        f32x4 sv[4];
#pragma unroll
        for (int kt = 0; kt < 4; ++kt) {
            f32x4 c;
            if (USE_COMB) {
                c[0] = bflo(cb[qt][kt].x);
                c[1] = bfhi(cb[qt][kt].x);
                c[2] = bflo(cb[qt][kt].y);
                c[3] = bfhi(cb[qt][kt].y);
            } else {
                const int q = qt * 16 + l15;
#pragma unroll
                for (int r = 0; r < 4; ++r) {
                    const int key = kt * 16 + lhi * 4 + r;
                    float v;
                    if (key >= NTOK)    v = -1e30f;
                    else if (q >= NTOK) v = 0.0f;
                    else v = rpb[rel[q * NTOK + key] * NHEAD + h] +
                             mask[(size_t)wm * (NTOK * NTOK) + q * NTOK + key];
                    c[r] = v;
                }
            }
            sv[kt] = MFMA(kf[kt], qf[qt], c, 0, 0, 0);
        }
        // softmax over keys: 16 in-lane + lanes {l15, l15+16, l15+32, l15+48}
        float m = sv[0][0];
#pragma unroll
        for (int kt = 0; kt < 4; ++kt)
#pragma unroll
            for (int r = 0; r < 4; ++r) m = fmaxf(m, sv[kt][r]);
        m = fmaxf(m, __shfl_xor(m, 16));
        m = fmaxf(m, __shfl_xor(m, 32));
        float sum = 0.f;
#pragma unroll
        for (int kt = 0; kt < 4; ++kt)
#pragma unroll
            for (int r = 0; r < 4; ++r) {
                const float p = __expf(sv[kt][r] - m);
                sv[kt][r] = p;
                sum += p;
            }
        sum += __shfl_xor(sum, 16);
        sum += __shfl_xor(sum, 32);
        inv[qt] = 1.0f / sum;
#pragma unroll
        for (int kt = 0; kt < 4; ++kt) {
            pw[qt][kt][0] = pack2bf(sv[kt][0], sv[kt][1]);
            pw[qt][kt][1] = pack2bf(sv[kt][2], sv[kt][3]);
        }
    }
    __syncthreads();  // b2: qk reads done everywhere; P may alias qk region

    unsigned char* Ph = smem + 16384 + h * 8192;  // P_h bf16 [64 q][64 key] swz
#pragma unroll
    for (int qt = 0; qt < 4; ++qt) {
        const int q = qt * 16 + l15;
#pragma unroll
        for (int kt = 0; kt < 4; ++kt) {
            const int colB = (kt * 16 + lhi * 4) * 2;
            uint2 u;
            u.x = pw[qt][kt][0];
            u.y = pw[qt][kt][1];
            *reinterpret_cast<uint2*>(&Ph[q * 128 + (colB ^ ((q & 7) << 4))]) = u;
        }
    }
    __syncthreads();  // b3: P visible; vt reads already done -> attnout may alias vt

    // PV (swapped): o[dt] lane holds O[d=h*32+16dt+lhi*4+r][q=16qt+l15]
#pragma unroll
    for (int qt = 0; qt < 4; ++qt) {
        bf16x8 pf[2];
        const int q = qt * 16 + l15;
#pragma unroll
        for (int ks = 0; ks < 2; ++ks) {
            const int colB = (ks * 32 + lhi * 8) * 2;
            pf[ks] = *reinterpret_cast<const bf16x8*>(&Ph[q * 128 + (colB ^ ((q & 7) << 4))]);
        }
        f32x4 o0 = {0.f, 0.f, 0.f, 0.f}, o1 = {0.f, 0.f, 0.f, 0.f};
#pragma unroll
        for (int ks = 0; ks < 2; ++ks) {
            o0 = MFMA(vf[0][ks], pf[ks], o0, 0, 0, 0);
            o1 = MFMA(vf[1][ks], pf[ks], o1, 0, 0, 0);
        }
        const float iv = inv[qt];
#pragma unroll
        for (int dt = 0; dt < 2; ++dt) {
            const f32x4 o = dt ? o1 : o0;
            const int chb = h * 32 + dt * 16 + lhi * 4;
            uint2 u;
            u.x = pack2bf(o[0] * iv, o[1] * iv);
            u.y = pack2bf(o[2] * iv, o[3] * iv);
            *reinterpret_cast<uint2*>(&smem[q * 256 + ((chb * 2) ^ ((q & 7) << 4))]) = u;
        }
    }
    __syncthreads();  // b4: attnout ready

    // ---------- phase 3: proj (swapped) -> float4 stores ----------
    bf16x8 aof[4][4];
#pragma unroll
    for (int tt = 0; tt < 4; ++tt)
#pragma unroll
        for (int ks = 0; ks < 4; ++ks) {
            const int tok = tt * 16 + l15;
            const int colB = (ks * 32 + lhi * 8) * 2;
            aof[tt][ks] = *reinterpret_cast<const bf16x8*>(&smem[tok * 256 + (colB ^ ((tok & 7) << 4))]);
        }
#pragma unroll
    for (int ct = 0; ct < 2; ++ct) {
        const int ocb = wid * 32 + ct * 16;
        bf16x8 wf[4];
#pragma unroll
        for (int ks = 0; ks < 4; ++ks)
            wf[ks] = *reinterpret_cast<const bf16x8*>(wp + (ocb + l15) * CDIM + ks * 32 + lhi * 8);
        const float4 pb4 = *reinterpret_cast<const float4*>(proj_b + ocb + lhi * 4);
#pragma unroll
        for (int tt = 0; tt < 4; ++tt) {
            f32x4 c = {0.f, 0.f, 0.f, 0.f};
#pragma unroll
            for (int ks = 0; ks < 4; ++ks) c = MFMA(wf[ks], aof[tt][ks], c, 0, 0, 0);
            const int tok = tt * 16 + l15;
            if (tok < NTOK) {
                float4 r;
                r.x = c[0] + pb4.x;
                r.y = c[1] + pb4.y;
                r.z = c[2] + pb4.z;
                r.w = c[3] + pb4.w;
                *reinterpret_cast<float4*>(out + (size_t)win * (NTOK * CDIM) + tok * CDIM + ocb + lhi * 4) = r;
            }
        }
    }
}

extern "C" void kernel_launch(void* const* d_in, const int* in_sizes, int n_in,
                              void* d_out, int out_size, void* d_ws, size_t ws_size,
                              hipStream_t stream) {
    const float* x      = (const float*)d_in[0];
    const float* mask   = (const float*)d_in[1];
    const float* qkv_w  = (const float*)d_in[2];
    const float* qkv_b  = (const float*)d_in[3];
    const float* proj_w = (const float*)d_in[4];
    const float* proj_b = (const float*)d_in[5];
    const float* rpb    = (const float*)d_in[6];
    const int*   rel    = (const int*)d_in[7];

    const int Bw = in_sizes[0] / (NTOK * CDIM);   // 16384
    const int nW = in_sizes[1] / (NTOK * NTOK);   // 1024

    unsigned short* wq   = (unsigned short*)d_ws;            // 384*128 bf16
    unsigned short* wp   = wq + 384 * 128;                   // 128*128 bf16
    unsigned short* comb = wp + 128 * 128;                   // nW*4*64*64 bf16
    const size_t need = (size_t)(384 * 128 + 128 * 128) * 2 + (size_t)nW * NHEAD * 4096 * 2;

    prep_w<<<dim3(192), dim3(256), 0, stream>>>(qkv_w, proj_w, wq, wp);
    if (ws_size >= need) {
        const int nComb = nW * NHEAD * 4096;
        prep_comb<<<dim3((nComb + 255) / 256), dim3(256), 0, stream>>>(mask, rpb, rel, comb, nW);
        win_attn_kernel<true><<<dim3(Bw), dim3(256), 0, stream>>>(
            x, qkv_b, proj_b, wq, wp, comb, mask, rpb, rel, (float*)d_out, nW);
    } else {
        win_attn_kernel<false><<<dim3(Bw), dim3(256), 0, stream>>>(
            x, qkv_b, proj_b, wq, wp, nullptr, mask, rpb, rel, (float*)d_out, nW);
    }
}

// Round 3
// 613.377 us; speedup vs baseline: 1.3243x; 1.0743x over previous
//
#include <hip/hip_runtime.h>
#include <hip/hip_bf16.h>

// WindowAttention fused kernel for MI355X (gfx950) — R2.
// Head-partitioned: wave h owns head h end-to-end (QKV -> attn -> PV) in a
// private 8KB LDS slice (same-wave DS ops are in-order -> no barriers).
// Only 2 barriers total (attnout exchange for proj). 32KB LDS, 4 blocks/CU.
// All bf16 packing via v_cvt_pk_bf16_f32 (__float22bfloat162_rn).
// Softmax in exp2 domain: log2e folded into Q-scale and comb table.

typedef short bf16x8 __attribute__((ext_vector_type(8)));
typedef float f32x4 __attribute__((ext_vector_type(4)));
#define MFMA __builtin_amdgcn_mfma_f32_16x16x32_bf16

#define NTOK 49
#define CDIM 128
#define NHEAD 4
#define LOG2E 1.4426950408889634f

__device__ __forceinline__ unsigned short f2bf(float f) {  // prep kernels only
    unsigned int u = __float_as_uint(f);
    u += 0x7fffu + ((u >> 16) & 1u);
    return (unsigned short)(u >> 16);
}
__device__ __forceinline__ unsigned pk2(float a, float b) {
    union { __hip_bfloat162 h; unsigned u; } t;
    t.h = __float22bfloat162_rn(make_float2(a, b));
    return t.u;
}
__device__ __forceinline__ float bflo(unsigned u) { return __uint_as_float(u << 16); }
__device__ __forceinline__ float bfhi(unsigned u) { return __uint_as_float(u & 0xffff0000u); }

union BF8 { bf16x8 v; unsigned u[4]; };

__global__ void prep_w(const float* __restrict__ qkv_w, const float* __restrict__ proj_w,
                       unsigned short* __restrict__ wq, unsigned short* __restrict__ wp) {
    int i = blockIdx.x * 256 + threadIdx.x;
    if (i < 384 * 128) wq[i] = f2bf(qkv_w[i]);   // [out_ch][in_ch] row-major
    if (i < 128 * 128) wp[i] = f2bf(proj_w[i]);
}

// comb[wm][h][q64][key64] bf16 = (rpb[rel[q][k]][h] + mask[wm][q][k]) * LOG2E
// pads: key>=49 -> -1e30, q>=49 -> 0
__global__ void prep_comb(const float* __restrict__ mask, const float* __restrict__ rpb,
                          const int* __restrict__ rel, unsigned short* __restrict__ comb, int nW) {
    int idx = blockIdx.x * 256 + threadIdx.x;
    int key = idx & 63;
    int q   = (idx >> 6) & 63;
    int h   = (idx >> 12) & 3;
    int wm  = idx >> 14;
    if (wm >= nW) return;
    float v;
    if (key >= NTOK)      v = -1e30f;
    else if (q >= NTOK)   v = 0.0f;
    else v = (rpb[rel[q * NTOK + key] * NHEAD + h] +
              mask[(size_t)wm * (NTOK * NTOK) + q * NTOK + key]) * LOG2E;
    comb[idx] = f2bf(v);
}

// LDS (32 KB): 4 per-head slices of 8 KB.
//  slice phase A: qk bf16[64 tok][64 ch] (Q ch 0-31, K ch 32-63), stride 128B, swz
//  slice phase B: vt bf16[32 ch][64 tok] @ +0 (4KB) | P ping-pong [16 q][64 key] @ +4096/+6144
//  after b1: attnout bf16[64 tok][128 ch] @ smem[0,16384) (aliases slices 0,1)
template <bool USE_COMB>
__global__ void __launch_bounds__(256, 4)
win_attn_kernel(const float* __restrict__ x,
                const float* __restrict__ qkv_b, const float* __restrict__ proj_b,
                const unsigned short* __restrict__ wq, const unsigned short* __restrict__ wp,
                const unsigned short* __restrict__ comb,
                const float* __restrict__ mask, const float* __restrict__ rpb,
                const int* __restrict__ rel,
                float* __restrict__ out, int nW) {
    __shared__ __align__(16) unsigned char smem[32768];

    const int tid = threadIdx.x;
    const int wid = tid >> 6;
    const int lane = tid & 63;
    const int l15 = lane & 15;
    const int lhi = lane >> 4;
    const int win = blockIdx.x;
    const int wm  = win % nW;
    const int h   = wid;
    unsigned char* slice = smem + h * 8192;
    const int swz = (l15 & 7) << 4;   // all our LDS rows satisfy row%16 == l15

    // ---------- x fragments from global (B operand: n=tok=l15, k=in_ch=8lhi+j) ----------
    const float* xw = x + (size_t)win * (NTOK * CDIM);
    bf16x8 xf[4][4];
#pragma unroll
    for (int tt = 0; tt < 4; ++tt) {
        const int tok = tt * 16 + l15;
        const bool valid = (tt < 3) || (l15 == 0);
#pragma unroll
        for (int ks = 0; ks < 4; ++ks) {
            float4 a = {0.f, 0.f, 0.f, 0.f}, b = {0.f, 0.f, 0.f, 0.f};
            if (valid) {
                const float* p = xw + tok * CDIM + ks * 32 + lhi * 8;
                a = reinterpret_cast<const float4*>(p)[0];
                b = reinterpret_cast<const float4*>(p)[1];
            }
            BF8 t;
            t.u[0] = pk2(a.x, a.y); t.u[1] = pk2(a.z, a.w);
            t.u[2] = pk2(b.x, b.y); t.u[3] = pk2(b.z, b.w);
            xf[tt][ks] = t.v;
        }
    }

    // ---------- phase 1a: Q,K for head h (swapped mfma -> 4 consecutive ch per lane) ----------
    const float qsc = 0.17677669529663687f * LOG2E;   // 1/sqrt(32) * log2(e)
#pragma unroll
    for (int cc = 0; cc < 4; ++cc) {
        const int cbase = (cc < 2) ? (h * 32 + cc * 16) : (128 + h * 32 + (cc - 2) * 16);
        bf16x8 wf[4];
#pragma unroll
        for (int ks = 0; ks < 4; ++ks)
            wf[ks] = *reinterpret_cast<const bf16x8*>(wq + (cbase + l15) * CDIM + ks * 32 + lhi * 8);
        const float4 b4 = *reinterpret_cast<const float4*>(qkv_b + cbase + lhi * 4);
        const float sc = (cc < 2) ? qsc : 1.0f;
#pragma unroll
        for (int tt = 0; tt < 4; ++tt) {
            f32x4 acc = {0.f, 0.f, 0.f, 0.f};
#pragma unroll
            for (int ks = 0; ks < 4; ++ks) acc = MFMA(wf[ks], xf[tt][ks], acc, 0, 0, 0);
            const int tok = tt * 16 + l15;
            uint2 u;
            u.x = pk2((acc[0] + b4.x) * sc, (acc[1] + b4.y) * sc);
            u.y = pk2((acc[2] + b4.z) * sc, (acc[3] + b4.w) * sc);
            *reinterpret_cast<uint2*>(&slice[tok * 128 + (((cc * 16 + lhi * 4) * 2) ^ swz)]) = u;
        }
    }

    // ---------- phase 1b: V for head h (normal mfma -> 4 consecutive toks per lane), keep in regs ----------
    uint2 vu[2][4];
#pragma unroll
    for (int cc = 0; cc < 2; ++cc) {
        const int cbase = 256 + h * 32 + cc * 16;
        bf16x8 wf[4];
#pragma unroll
        for (int ks = 0; ks < 4; ++ks)
            wf[ks] = *reinterpret_cast<const bf16x8*>(wq + (cbase + l15) * CDIM + ks * 32 + lhi * 8);
        const float bs = qkv_b[cbase + l15];
#pragma unroll
        for (int tt = 0; tt < 4; ++tt) {
            f32x4 acc = {0.f, 0.f, 0.f, 0.f};
#pragma unroll
            for (int ks = 0; ks < 4; ++ks) acc = MFMA(xf[tt][ks], wf[ks], acc, 0, 0, 0);
            vu[cc][tt].x = pk2(acc[0] + bs, acc[1] + bs);
            vu[cc][tt].y = pk2(acc[2] + bs, acc[3] + bs);
        }
    }

    // ---------- per-wave LDS: read qf/kf, then overwrite with vt (same-wave DS is in-order) ----------
    bf16x8 qf[4], kf[4];
#pragma unroll
    for (int t = 0; t < 4; ++t) {
        const int row = t * 16 + l15;
        qf[t] = *reinterpret_cast<const bf16x8*>(&slice[row * 128 + ((16 * lhi) ^ swz)]);
        kf[t] = *reinterpret_cast<const bf16x8*>(&slice[row * 128 + ((64 + 16 * lhi) ^ swz)]);
    }
#pragma unroll
    for (int cc = 0; cc < 2; ++cc) {
        const int vr = cc * 16 + l15;
#pragma unroll
        for (int tt = 0; tt < 4; ++tt)
            *reinterpret_cast<uint2*>(&slice[vr * 128 + (((tt * 16 + lhi * 4) * 2) ^ swz)]) = vu[cc][tt];
    }
    bf16x8 vf[2][2];
#pragma unroll
    for (int dt = 0; dt < 2; ++dt)
#pragma unroll
        for (int ks = 0; ks < 2; ++ks)
            vf[dt][ks] = *reinterpret_cast<const bf16x8*>(
                &slice[(dt * 16 + l15) * 128 + (((ks * 32 + lhi * 8) * 2) ^ swz)]);

    // ---------- phase 2: attention for head h (no barriers; P ping-pong in private slice) ----------
    const unsigned short* cwh = comb + ((size_t)(wm * NHEAD + h) << 12);
    uint2 cb[4];
    if (USE_COMB) {
#pragma unroll
        for (int kt = 0; kt < 4; ++kt)
            cb[kt] = *reinterpret_cast<const uint2*>(cwh + l15 * 64 + kt * 16 + lhi * 4);
    }
    float inv[4];
    uint2 ou[4][2];
#pragma unroll
    for (int qt = 0; qt < 4; ++qt) {
        uint2 cbn[4];
        if (USE_COMB && qt < 3) {
#pragma unroll
            for (int kt = 0; kt < 4; ++kt)
                cbn[kt] = *reinterpret_cast<const uint2*>(cwh + ((qt + 1) * 16 + l15) * 64 + kt * 16 + lhi * 4);
        }
        f32x4 sv[4];
#pragma unroll
        for (int kt = 0; kt < 4; ++kt) {
            f32x4 c;
            if (USE_COMB) {
                c[0] = bflo(cb[kt].x); c[1] = bfhi(cb[kt].x);
                c[2] = bflo(cb[kt].y); c[3] = bfhi(cb[kt].y);
            } else {
                const int q = qt * 16 + l15;
#pragma unroll
                for (int r = 0; r < 4; ++r) {
                    const int key = kt * 16 + lhi * 4 + r;
                    float v;
                    if (key >= NTOK)    v = -1e30f;
                    else if (q >= NTOK) v = 0.0f;
                    else v = (rpb[rel[q * NTOK + key] * NHEAD + h] +
                              mask[(size_t)wm * (NTOK * NTOK) + q * NTOK + key]) * LOG2E;
                    c[r] = v;
                }
            }
            sv[kt] = MFMA(kf[kt], qf[qt], c, 0, 0, 0);   // S[key=16kt+4lhi+r][q=16qt+l15] (log2 domain)
        }
        // softmax over keys (16 in-lane + cross-lhi via shfl_xor 16,32)
        float m = sv[0][0];
#pragma unroll
        for (int kt = 0; kt < 4; ++kt)
#pragma unroll
            for (int r = 0; r < 4; ++r) m = fmaxf(m, sv[kt][r]);
        m = fmaxf(m, __shfl_xor(m, 16));
        m = fmaxf(m, __shfl_xor(m, 32));
        float sum = 0.f;
#pragma unroll
        for (int kt = 0; kt < 4; ++kt)
#pragma unroll
            for (int r = 0; r < 4; ++r) {
                const float p = exp2f(sv[kt][r] - m);
                sv[kt][r] = p;
                sum += p;
            }
        sum += __shfl_xor(sum, 16);
        sum += __shfl_xor(sum, 32);
        inv[qt] = __builtin_amdgcn_rcpf(sum);
        // write unnormalized P to ping-pong buffer [16 q][64 key]
        unsigned char* Pb = slice + 4096 + (qt & 1) * 2048;
#pragma unroll
        for (int kt = 0; kt < 4; ++kt) {
            uint2 u;
            u.x = pk2(sv[kt][0], sv[kt][1]);
            u.y = pk2(sv[kt][2], sv[kt][3]);
            *reinterpret_cast<uint2*>(&Pb[l15 * 128 + (((kt * 16 + lhi * 4) * 2) ^ swz)]) = u;
        }
        bf16x8 pf0 = *reinterpret_cast<const bf16x8*>(&Pb[l15 * 128 + ((lhi * 16) ^ swz)]);
        bf16x8 pf1 = *reinterpret_cast<const bf16x8*>(&Pb[l15 * 128 + ((64 + lhi * 16) ^ swz)]);
        // PV: O[d=16dt+4lhi+r][q=16qt+l15]
        f32x4 o0 = {0.f, 0.f, 0.f, 0.f}, o1 = {0.f, 0.f, 0.f, 0.f};
        o0 = MFMA(vf[0][0], pf0, o0, 0, 0, 0);
        o0 = MFMA(vf[0][1], pf1, o0, 0, 0, 0);
        o1 = MFMA(vf[1][0], pf0, o1, 0, 0, 0);
        o1 = MFMA(vf[1][1], pf1, o1, 0, 0, 0);
        const float iv = inv[qt];
        ou[qt][0].x = pk2(o0[0] * iv, o0[1] * iv);
        ou[qt][0].y = pk2(o0[2] * iv, o0[3] * iv);
        ou[qt][1].x = pk2(o1[0] * iv, o1[1] * iv);
        ou[qt][1].y = pk2(o1[2] * iv, o1[3] * iv);
        if (USE_COMB && qt < 3) {
#pragma unroll
            for (int kt = 0; kt < 4; ++kt) cb[kt] = cbn[kt];
        }
    }

    // ---------- prefetch proj weights/bias (independent of LDS) ----------
    bf16x8 wpf[2][4];
    float4 pb4[2];
#pragma unroll
    for (int ct = 0; ct < 2; ++ct) {
        const int ocb = wid * 32 + ct * 16;
#pragma unroll
        for (int ks = 0; ks < 4; ++ks)
            wpf[ct][ks] = *reinterpret_cast<const bf16x8*>(wp + (ocb + l15) * CDIM + ks * 32 + lhi * 8);
        pb4[ct] = *reinterpret_cast<const float4*>(proj_b + ocb + lhi * 4);
    }

    __syncthreads();  // b1: all private-slice reads done -> attnout may alias slices 0,1

    // attnout[64 tok][128 ch] bf16 @ smem[0,16384), stride 256B, swz
#pragma unroll
    for (int qt = 0; qt < 4; ++qt) {
        const int row = qt * 16 + l15;
#pragma unroll
        for (int dt = 0; dt < 2; ++dt)
            *reinterpret_cast<uint2*>(
                &smem[row * 256 + (((h * 32 + dt * 16 + lhi * 4) * 2) ^ swz)]) = ou[qt][dt];
    }
    __syncthreads();  // b2: attnout ready

    // ---------- phase 3: proj (swapped) -> float4 stores ----------
    bf16x8 aof[4][4];
#pragma unroll
    for (int tt = 0; tt < 4; ++tt)
#pragma unroll
        for (int ks = 0; ks < 4; ++ks) {
            const int row = tt * 16 + l15;
            aof[tt][ks] = *reinterpret_cast<const bf16x8*>(
                &smem[row * 256 + (((ks * 32 + lhi * 8) * 2) ^ swz)]);
        }
#pragma unroll
    for (int ct = 0; ct < 2; ++ct) {
        const int ocb = wid * 32 + ct * 16;
#pragma unroll
        for (int tt = 0; tt < 4; ++tt) {
            f32x4 c = {0.f, 0.f, 0.f, 0.f};
#pragma unroll
            for (int ks = 0; ks < 4; ++ks) c = MFMA(wpf[ct][ks], aof[tt][ks], c, 0, 0, 0);
            const int tok = tt * 16 + l15;
            if (tok < NTOK) {
                float4 r;
                r.x = c[0] + pb4[ct].x;
                r.y = c[1] + pb4[ct].y;
                r.z = c[2] + pb4[ct].z;
                r.w = c[3] + pb4[ct].w;
                *reinterpret_cast<float4*>(out + (size_t)win * (NTOK * CDIM) + tok * CDIM + ocb + lhi * 4) = r;
            }
        }
    }
}

extern "C" void kernel_launch(void* const* d_in, const int* in_sizes, int n_in,
                              void* d_out, int out_size, void* d_ws, size_t ws_size,
                              hipStream_t stream) {
    const float* x      = (const float*)d_in[0];
    const float* mask   = (const float*)d_in[1];
    const float* qkv_w  = (const float*)d_in[2];
    const float* qkv_b  = (const float*)d_in[3];
    const float* proj_w = (const float*)d_in[4];
    const float* proj_b = (const float*)d_in[5];
    const float* rpb    = (const float*)d_in[6];
    const int*   rel    = (const int*)d_in[7];

    const int Bw = in_sizes[0] / (NTOK * CDIM);   // 16384
    const int nW = in_sizes[1] / (NTOK * NTOK);   // 1024

    unsigned short* wq   = (unsigned short*)d_ws;            // 384*128 bf16
    unsigned short* wp   = wq + 384 * 128;                   // 128*128 bf16
    unsigned short* comb = wp + 128 * 128;                   // nW*4*64*64 bf16
    const size_t need = (size_t)(384 * 128 + 128 * 128) * 2 + (size_t)nW * NHEAD * 4096 * 2;

    prep_w<<<dim3(192), dim3(256), 0, stream>>>(qkv_w, proj_w, wq, wp);
    if (ws_size >= need) {
        const int nComb = nW * NHEAD * 4096;
        prep_comb<<<dim3((nComb + 255) / 256), dim3(256), 0, stream>>>(mask, rpb, rel, comb, nW);
        win_attn_kernel<true><<<dim3(Bw), dim3(256), 0, stream>>>(
            x, qkv_b, proj_b, wq, wp, comb, mask, rpb, rel, (float*)d_out, nW);
    } else {
        win_attn_kernel<false><<<dim3(Bw), dim3(256), 0, stream>>>(
            x, qkv_b, proj_b, wq, wp, nullptr, mask, rpb, rel, (float*)d_out, nW);
    }
}